// Round 2
// baseline (731.471 us; speedup 1.0000x reference)
//
#include <hip/hip_runtime.h>
#include <math.h>

#define BB 8
#define TXT_T 200
#define MEL_T 800
#define N_MEL 80
#define PAD_MAG 1.0e12f
#define LPT_STRIDE 200   // floats per row of lpT (j dim); 800B, 16B-aligned

__device__ __forceinline__ float laddexp(float a, float b) {
    // reference: logaddexp(a + 1e-7, b + 1e-7)
    float p = a + 1e-7f;
    float q = b + 1e-7f;
    float m = fmaxf(p, q);
    float d = fabsf(p - q);
    return m + log1pf(__expf(-d));
}

// Kernel 1: lp[b,t,m] = -0.5/80 * ( sum_n (x-mu)^2*exp(-lv) + sum_n lv )
// writes lp to out_lp [B][TXT_T][MEL_T] and transposed lpT [B][MEL_T][TXT_T]
__global__ void __launch_bounds__(256) lp_kernel(
        const float* __restrict__ mu_logvar,   // [B][TXT_T][160]
        const float* __restrict__ melspec,     // [B][N_MEL][MEL_T]
        float* __restrict__ out_lp,            // -> d_out + 1
        float* __restrict__ lpT) {
    const int bt = blockIdx.x;            // b*TXT_T + t
    const int b  = bt / TXT_T;
    const int t  = bt % TXT_T;
    const int tid = threadIdx.x;

    __shared__ float s_mu[N_MEL];
    __shared__ float s_ev[N_MEL];
    __shared__ float s_lv[N_MEL];
    __shared__ float s_sumlv;

    if (tid < N_MEL) {
        float mu = mu_logvar[(size_t)bt * (2 * N_MEL) + tid];
        float lv = mu_logvar[(size_t)bt * (2 * N_MEL) + N_MEL + tid];
        s_mu[tid] = mu;
        s_ev[tid] = __expf(-lv);
        s_lv[tid] = lv;
    }
    __syncthreads();
    if (tid == 0) {
        float s = 0.f;
        #pragma unroll
        for (int n = 0; n < N_MEL; ++n) s += s_lv[n];
        s_sumlv = s;
    }
    __syncthreads();

    if (tid < MEL_T / 4) {
        const float4* ms4 = (const float4*)(melspec + (size_t)b * N_MEL * MEL_T);
        float ax = 0.f, ay = 0.f, az = 0.f, aw = 0.f;
        #pragma unroll 8
        for (int n = 0; n < N_MEL; ++n) {
            float4 x = ms4[(size_t)n * (MEL_T / 4) + tid];
            float mu = s_mu[n];
            float ev = s_ev[n];
            float d0 = x.x - mu; ax += d0 * d0 * ev;
            float d1 = x.y - mu; ay += d1 * d1 * ev;
            float d2 = x.z - mu; az += d2 * d2 * ev;
            float d3 = x.w - mu; aw += d3 * d3 * ev;
        }
        const float c = -0.5f / (float)N_MEL;
        float slv = s_sumlv;
        float l0 = c * (ax + slv);
        float l1 = c * (ay + slv);
        float l2 = c * (az + slv);
        float l3 = c * (aw + slv);

        size_t ob = (size_t)bt * MEL_T + tid * 4;
        out_lp[ob + 0] = l0;
        out_lp[ob + 1] = l1;
        out_lp[ob + 2] = l2;
        out_lp[ob + 3] = l3;

        // transposed write: lpT[b][m][t]
        int m0 = tid * 4;
        size_t tb = ((size_t)b * MEL_T + m0) * LPT_STRIDE + t;
        lpT[tb + 0 * LPT_STRIDE] = l0;
        lpT[tb + 1 * LPT_STRIDE] = l1;
        lpT[tb + 2 * LPT_STRIDE] = l2;
        lpT[tb + 3 * LPT_STRIDE] = l3;
    }
}

// Kernel 2: serial scan over mel steps, one wave per batch.
// r[j] (j=0..199) lives in registers, 4 per lane (lanes 0..49 hold valid j).
// 100 fully-unrolled chunks of 8 steps (tt=1..800); prefetch rows clamped to
// 799. Step tt=800 is an extra harmless step (alpha gather fires at
// tt==melL1 <= 799 and nothing later writes alpha_out). NO break in the
// unrolled body — keeps buf[] statically indexed (registers, not scratch).
__global__ void __launch_bounds__(64) scan_kernel(
        const float* __restrict__ lpT,          // [B][MEL_T][LPT_STRIDE]
        const int* __restrict__ text_lengths,
        const int* __restrict__ mel_lengths,
        float* __restrict__ alpha_out) {        // [B]
    const int b = blockIdx.x;
    const int lane = threadIdx.x;
    const float* base = lpT + (size_t)b * MEL_T * LPT_STRIDE;

    int j0 = lane * 4;
    int jc = j0 > (TXT_T - 4) ? (TXT_T - 4) : j0;   // clamp lanes 50..63 in-bounds

    const int melL1 = mel_lengths[b] - 1;
    const int txtL1 = text_lengths[b] - 1;
    const float inv_mel = 1.0f / (float)(melL1 + 1);
    const int alane = txtL1 >> 2;
    const int acomp = txtL1 & 3;

    float r0 = -PAD_MAG, r1 = -PAD_MAG, r2 = -PAD_MAG, r3 = -PAD_MAG;
    float lp00 = base[0];
    if (lane == 0) r0 = lp00;

    if (melL1 == 0 && lane == alane) {
        float v = (acomp == 0) ? r0 : (acomp == 1) ? r1 : (acomp == 2) ? r2 : r3;
        alpha_out[b] = v * inv_mel;
    }

    const int PF = 8;
    float4 buf[PF];
    #pragma unroll
    for (int k = 0; k < PF; ++k) {
        buf[k] = *(const float4*)(base + (size_t)(1 + k) * LPT_STRIDE + jc);
    }

    for (int t = 1; t < MEL_T; t += PF) {   // t = 1,9,...,793 -> 100 chunks
        #pragma unroll
        for (int k = 0; k < PF; ++k) {
            const int tt = t + k;
            float4 lp = buf[k];
            // prefetch PF steps ahead (row clamped; clamped rows' data is
            // consumed only by the harmless overrun step)
            int row = tt + PF;
            row = row > (MEL_T - 1) ? (MEL_T - 1) : row;
            buf[k] = *(const float4*)(base + (size_t)row * LPT_STRIDE + jc);

            float left = __shfl_up(r3, 1);
            if (lane == 0) left = -PAD_MAG;   // a[0] stays -PAD forever
            float n0 = laddexp(r0, left) + lp.x;
            float n1 = laddexp(r1, r0)   + lp.y;
            float n2 = laddexp(r2, r1)   + lp.z;
            float n3 = laddexp(r3, r2)   + lp.w;
            r0 = n0; r1 = n1; r2 = n2; r3 = n3;

            if (tt == melL1 && lane == alane) {
                float v = (acomp == 0) ? r0 : (acomp == 1) ? r1
                        : (acomp == 2) ? r2 : r3;
                alpha_out[b] = v * inv_mel;
            }
        }
    }
}

// Kernel 3: loss = -mean_b alpha[b]
__global__ void finish_kernel(const float* __restrict__ alpha,
                              float* __restrict__ out) {
    float s = 0.f;
    #pragma unroll
    for (int b = 0; b < BB; ++b) s += alpha[b];
    out[0] = -(s / (float)BB);
}

extern "C" void kernel_launch(void* const* d_in, const int* in_sizes, int n_in,
                              void* d_out, int out_size, void* d_ws, size_t ws_size,
                              hipStream_t stream) {
    const float* mu_logvar    = (const float*)d_in[0];
    const float* melspec      = (const float*)d_in[1];
    const int*   text_lengths = (const int*)d_in[2];
    const int*   mel_lengths  = (const int*)d_in[3];
    float* out = (float*)d_out;

    float* alpha = (float*)d_ws;                 // 8 floats
    float* lpT   = (float*)d_ws + 16;            // 64B offset, [B][MEL_T][LPT_STRIDE]

    lp_kernel<<<BB * TXT_T, 256, 0, stream>>>(mu_logvar, melspec, out + 1, lpT);
    scan_kernel<<<BB, 64, 0, stream>>>(lpT, text_lengths, mel_lengths, alpha);
    finish_kernel<<<1, 1, 0, stream>>>(alpha, out);
}

// Round 4
// 158.183 us; speedup vs baseline: 4.6242x; 4.6242x over previous
//
#include <hip/hip_runtime.h>
#include <math.h>

#define BB 8
#define TXT_T 200
#define MEL_T 800
#define N_MEL 80
#define PAD_MAG 1.0e12f
#define LPT_STRIDE 200   // floats per row of lpT (j dim); 800B, 16B-aligned

// reference: logaddexp(a+1e-7, b+1e-7) = max+1e-7 + ln(1+exp(-|a-b|))
// __expf/__log2f map to HW v_exp_f32/v_log_f32 (short dep chain).
__device__ __forceinline__ float laddexp(float a, float b) {
    float m = fmaxf(a, b);
    float d = fabsf(a - b);
    float e = __expf(-d);   // e^{-d}
    return m + 1e-7f + 0.69314718055994530942f * __log2f(1.0f + e);
}

// Kernel 1: lp[b,t,m] = -0.5/80 * ( sum_n (x-mu)^2*exp(-lv) + sum_n lv )
// writes lp to out_lp [B][TXT_T][MEL_T] and transposed lpT [B][MEL_T][TXT_T]
__global__ void __launch_bounds__(256) lp_kernel(
        const float* __restrict__ mu_logvar,   // [B][TXT_T][160]
        const float* __restrict__ melspec,     // [B][N_MEL][MEL_T]
        float* __restrict__ out_lp,            // -> d_out + 1
        float* __restrict__ lpT) {
    const int bt = blockIdx.x;            // b*TXT_T + t
    const int b  = bt / TXT_T;
    const int t  = bt % TXT_T;
    const int tid = threadIdx.x;

    __shared__ float s_mu[N_MEL];
    __shared__ float s_ev[N_MEL];
    __shared__ float s_lv[N_MEL];
    __shared__ float s_sumlv;

    if (tid < N_MEL) {
        float mu = mu_logvar[(size_t)bt * (2 * N_MEL) + tid];
        float lv = mu_logvar[(size_t)bt * (2 * N_MEL) + N_MEL + tid];
        s_mu[tid] = mu;
        s_ev[tid] = __expf(-lv);
        s_lv[tid] = lv;
    }
    __syncthreads();
    if (tid == 0) {
        float s = 0.f;
        #pragma unroll
        for (int n = 0; n < N_MEL; ++n) s += s_lv[n];
        s_sumlv = s;
    }
    __syncthreads();

    if (tid < MEL_T / 4) {
        const float4* ms4 = (const float4*)(melspec + (size_t)b * N_MEL * MEL_T);
        float ax = 0.f, ay = 0.f, az = 0.f, aw = 0.f;
        #pragma unroll 8
        for (int n = 0; n < N_MEL; ++n) {
            float4 x = ms4[(size_t)n * (MEL_T / 4) + tid];
            float mu = s_mu[n];
            float ev = s_ev[n];
            float d0 = x.x - mu; ax += d0 * d0 * ev;
            float d1 = x.y - mu; ay += d1 * d1 * ev;
            float d2 = x.z - mu; az += d2 * d2 * ev;
            float d3 = x.w - mu; aw += d3 * d3 * ev;
        }
        const float c = -0.5f / (float)N_MEL;
        float slv = s_sumlv;
        float l0 = c * (ax + slv);
        float l1 = c * (ay + slv);
        float l2 = c * (az + slv);
        float l3 = c * (aw + slv);

        size_t ob = (size_t)bt * MEL_T + tid * 4;
        out_lp[ob + 0] = l0;
        out_lp[ob + 1] = l1;
        out_lp[ob + 2] = l2;
        out_lp[ob + 3] = l3;

        // transposed write: lpT[b][m][t]
        int m0 = tid * 4;
        size_t tb = ((size_t)b * MEL_T + m0) * LPT_STRIDE + t;
        lpT[tb + 0 * LPT_STRIDE] = l0;
        lpT[tb + 1 * LPT_STRIDE] = l1;
        lpT[tb + 2 * LPT_STRIDE] = l2;
        lpT[tb + 3 * LPT_STRIDE] = l3;
    }
}

#define PF 8

// one scan step: consume VK (row TT), prefetch row TT+PF into VK, recur.
// VK is a NAMED float4 variable -> guaranteed registers (no runtime-indexed
// array => no scratch; rule #20).
#define STEP(VK, TT) do {                                                     \
    float4 lp_ = VK;                                                          \
    int row_ = (TT) + PF;                                                     \
    row_ = row_ > (MEL_T - 1) ? (MEL_T - 1) : row_;                           \
    VK = *(const float4*)(base + (size_t)row_ * LPT_STRIDE + jc);             \
    float left_ = __shfl_up(r3, 1);                                           \
    if (lane == 0) left_ = -PAD_MAG;  /* a[0] stays -PAD forever */           \
    float n0_ = laddexp(r0, left_) + lp_.x;                                   \
    float n1_ = laddexp(r1, r0)    + lp_.y;                                   \
    float n2_ = laddexp(r2, r1)    + lp_.z;                                   \
    float n3_ = laddexp(r3, r2)    + lp_.w;                                   \
    r0 = n0_; r1 = n1_; r2 = n2_; r3 = n3_;                                   \
    if ((TT) == melL1 && lane == alane) {                                     \
        float v_ = (acomp == 0) ? r0 : (acomp == 1) ? r1                      \
                 : (acomp == 2) ? r2 : r3;                                    \
        alpha_out[b] = v_ * inv_mel;                                          \
    }                                                                         \
} while (0)

// Kernel 2: serial scan over mel steps, one wave per batch.
// r[j] (j=0..199) in registers, 4 per lane (lanes 0..49 valid).
// 100 hand-unrolled chunks of 8 steps (tt=1..800); prefetch rows clamped to
// 799; the tt=800 overrun step is harmless (gather fires at tt==melL1<=799).
__global__ void __launch_bounds__(64) scan_kernel(
        const float* __restrict__ lpT,          // [B][MEL_T][LPT_STRIDE]
        const int* __restrict__ text_lengths,
        const int* __restrict__ mel_lengths,
        float* __restrict__ alpha_out) {        // [B]
    const int b = blockIdx.x;
    const int lane = threadIdx.x;
    const float* base = lpT + (size_t)b * MEL_T * LPT_STRIDE;

    int j0 = lane * 4;
    int jc = j0 > (TXT_T - 4) ? (TXT_T - 4) : j0;   // clamp lanes 50..63

    const int melL1 = mel_lengths[b] - 1;
    const int txtL1 = text_lengths[b] - 1;
    const float inv_mel = 1.0f / (float)(melL1 + 1);
    const int alane = txtL1 >> 2;
    const int acomp = txtL1 & 3;

    float r0 = -PAD_MAG, r1 = -PAD_MAG, r2 = -PAD_MAG, r3 = -PAD_MAG;
    float lp00 = base[0];
    if (lane == 0) r0 = lp00;

    if (melL1 == 0 && lane == alane) {
        float v = (acomp == 0) ? r0 : (acomp == 1) ? r1 : (acomp == 2) ? r2 : r3;
        alpha_out[b] = v * inv_mel;
    }

    // named prefetch ring, rows 1..8
    float4 v0 = *(const float4*)(base + (size_t)1 * LPT_STRIDE + jc);
    float4 v1 = *(const float4*)(base + (size_t)2 * LPT_STRIDE + jc);
    float4 v2 = *(const float4*)(base + (size_t)3 * LPT_STRIDE + jc);
    float4 v3 = *(const float4*)(base + (size_t)4 * LPT_STRIDE + jc);
    float4 v4 = *(const float4*)(base + (size_t)5 * LPT_STRIDE + jc);
    float4 v5 = *(const float4*)(base + (size_t)6 * LPT_STRIDE + jc);
    float4 v6 = *(const float4*)(base + (size_t)7 * LPT_STRIDE + jc);
    float4 v7 = *(const float4*)(base + (size_t)8 * LPT_STRIDE + jc);

    for (int t = 1; t < MEL_T; t += PF) {   // t = 1,9,...,793 -> 100 chunks
        STEP(v0, t + 0);
        STEP(v1, t + 1);
        STEP(v2, t + 2);
        STEP(v3, t + 3);
        STEP(v4, t + 4);
        STEP(v5, t + 5);
        STEP(v6, t + 6);
        STEP(v7, t + 7);
    }
}

// Kernel 3: loss = -mean_b alpha[b]
__global__ void finish_kernel(const float* __restrict__ alpha,
                              float* __restrict__ out) {
    float s = 0.f;
    #pragma unroll
    for (int b = 0; b < BB; ++b) s += alpha[b];
    out[0] = -(s / (float)BB);
}

extern "C" void kernel_launch(void* const* d_in, const int* in_sizes, int n_in,
                              void* d_out, int out_size, void* d_ws, size_t ws_size,
                              hipStream_t stream) {
    const float* mu_logvar    = (const float*)d_in[0];
    const float* melspec      = (const float*)d_in[1];
    const int*   text_lengths = (const int*)d_in[2];
    const int*   mel_lengths  = (const int*)d_in[3];
    float* out = (float*)d_out;

    float* alpha = (float*)d_ws;                 // 8 floats
    float* lpT   = (float*)d_ws + 16;            // 64B offset, [B][MEL_T][LPT_STRIDE]

    lp_kernel<<<BB * TXT_T, 256, 0, stream>>>(mu_logvar, melspec, out + 1, lpT);
    scan_kernel<<<BB, 64, 0, stream>>>(lpT, text_lengths, mel_lengths, alpha);
    finish_kernel<<<1, 1, 0, stream>>>(alpha, out);
}